// Round 2
// baseline (157.577 us; speedup 1.0000x reference)
//
#include <hip/hip_runtime.h>
#include <hip/hip_bf16.h>

// Problem constants: B=4, C=16, F=35, G=72, D=24, T=256
#define NB 4
#define NC 16
#define NF 35
#define NG 72
#define ND3 13824   // 24^3
#define NT 256
#define FP 36       // padded row stride (36*4B = 144B, 16B-multiple -> s_load_dwordx4)

// SELU constants (match jax.nn.selu)
#define SELU_LAMBDA 1.0507009873554805f
#define SELU_LA     1.7580993408473766f   // lambda * alpha

// ---------------------------------------------------------------------------
// Prep kernel (one tiny block): tb = t @ W_time^T + b_time, plus 16B-aligned
// padded copies of A_ift and A_ft^T in ws.
// ws floats: [0,64) tb | [64, 64+72*36) A_ift pad | next 72*36 A_ftT pad
// ---------------------------------------------------------------------------
__global__ __launch_bounds__(256) void fta_prep(
    const float* __restrict__ t, const float* __restrict__ A_ift,
    const float* __restrict__ A_ft, const float* __restrict__ W_time,
    const float* __restrict__ b_time, float* __restrict__ ws) {
  const int tid = threadIdx.x;
  if (tid < NB * NC) {
    const int b = tid / NC, c = tid % NC;
    float s = b_time[c];
    #pragma unroll 4
    for (int k = 0; k < NT; ++k) s = fmaf(t[b * NT + k], W_time[c * NT + k], s);
    ws[tid] = s;
  }
  float* aift_p = ws + 64;
  float* aftT_p = ws + 64 + NG * FP;
  for (int i = tid; i < NG * FP; i += 256) {
    const int g = i / FP, f = i % FP;
    aift_p[i] = (f < NF) ? A_ift[g * NF + f] : 0.0f;
    aftT_p[i] = (f < NF) ? A_ft[f * NG + g] : 0.0f;  // transpose of A_ft
  }
}

// ---------------------------------------------------------------------------
// Fused main kernel: one thread per voxel per (b,c).
// __launch_bounds__(256,4): VGPR cap 128 so xr[35]+acc[35] stay in registers
// (R1's default heuristic gave 40 VGPRs -> spill/rematerialize, 154us).
// v-dot is computed as 4 independent partial chains to cut FMA dep latency.
// ---------------------------------------------------------------------------
__global__ __launch_bounds__(256, 4) void fta_fused(
    const float* __restrict__ x_hat, const float* __restrict__ ws,
    float* __restrict__ out) {
  const int bc  = blockIdx.y;                       // 0..63  (b*C + c)
  const int vox = blockIdx.x * 256 + threadIdx.x;   // 0..13823 (54*256 exact)

  const float tb = ws[bc];
  const float* __restrict__ aift = (const float*)__builtin_assume_aligned(ws + 64, 16);
  const float* __restrict__ aftT = (const float*)__builtin_assume_aligned(ws + 64 + NG * FP, 16);

  const float* __restrict__ xp = x_hat + (size_t)bc * NF * ND3 + vox;

  float xr[NF];
  #pragma unroll
  for (int f = 0; f < NF; ++f) xr[f] = xp[(size_t)f * ND3];

  float acc[NF];
  #pragma unroll
  for (int f = 0; f < NF; ++f) acc[f] = 0.0f;

  #pragma unroll 2
  for (int g = 0; g < NG; ++g) {
    const float* __restrict__ arow = aift + g * FP;

    // 4-way split dot product: breaks the 35-deep serial FMA chain (~140cy)
    // into ~9-deep chains (~36cy) so 4 waves/SIMD can hide the latency.
    float v0 = tb, v1 = 0.0f, v2 = 0.0f, v3 = 0.0f;
    #pragma unroll
    for (int f = 0; f < 32; f += 4) {
      v0 = fmaf(arow[f + 0], xr[f + 0], v0);
      v1 = fmaf(arow[f + 1], xr[f + 1], v1);
      v2 = fmaf(arow[f + 2], xr[f + 2], v2);
      v3 = fmaf(arow[f + 3], xr[f + 3], v3);
    }
    v0 = fmaf(arow[32], xr[32], v0);
    v1 = fmaf(arow[33], xr[33], v1);
    v2 = fmaf(arow[34], xr[34], v2);
    const float v = (v0 + v1) + (v2 + v3);

    // SELU: lambda * (v > 0 ? v : alpha*(exp(v)-1))
    const float e   = __expf(v);
    const float neg = fmaf(SELU_LA, e, -SELU_LA);   // lambda*alpha*(e-1)
    const float pos = SELU_LAMBDA * v;
    const float y   = (v > 0.0f) ? pos : neg;

    const float* __restrict__ brow = aftT + g * FP;
    #pragma unroll
    for (int f = 0; f < NF; ++f) acc[f] = fmaf(brow[f], y, acc[f]);
  }

  float* __restrict__ op = out + (size_t)bc * NF * ND3 + vox;
  #pragma unroll
  for (int f = 0; f < NF; ++f) op[(size_t)f * ND3] = acc[f];
}

extern "C" void kernel_launch(void* const* d_in, const int* in_sizes, int n_in,
                              void* d_out, int out_size, void* d_ws, size_t ws_size,
                              hipStream_t stream) {
  const float* x_hat  = (const float*)d_in[0];
  const float* t      = (const float*)d_in[1];
  const float* A_ift  = (const float*)d_in[2];
  const float* A_ft   = (const float*)d_in[3];
  const float* W_time = (const float*)d_in[4];
  const float* b_time = (const float*)d_in[5];
  float* out = (float*)d_out;
  float* ws  = (float*)d_ws;   // needs 64 + 2*72*36 = 5248 floats = 21 KB

  fta_prep<<<1, 256, 0, stream>>>(t, A_ift, A_ft, W_time, b_time, ws);

  dim3 grid(ND3 / 256, NB * NC);   // (54, 64)
  fta_fused<<<grid, 256, 0, stream>>>(x_hat, ws, out);
}

// Round 3
// 155.175 us; speedup vs baseline: 1.0155x; 1.0155x over previous
//
#include <hip/hip_runtime.h>
#include <hip/hip_bf16.h>

// Problem constants: B=4, C=16, F=35, G=72, D=24, T=256
#define NB 4
#define NC 16
#define NF 35
#define NG 72
#define ND3 13824   // 24^3
#define NT 256
#define FP 36       // padded row stride (36*4B = 144B, 16B-multiple -> s_load_dwordx4)

// SELU constants (match jax.nn.selu)
#define SELU_LAMBDA 1.0507009873554805f
#define SELU_LA     1.7580993408473766f   // lambda * alpha

// ---------------------------------------------------------------------------
// Prep kernel: tb = t @ W_time^T + b_time, plus 16B-aligned padded copies of
// A_ift and A_ft^T in ws.
// ws floats: [0,64) tb | [64, 64+72*36) A_ift pad | next 72*36 A_ftT pad
// ---------------------------------------------------------------------------
__global__ __launch_bounds__(256) void fta_prep(
    const float* __restrict__ t, const float* __restrict__ A_ift,
    const float* __restrict__ A_ft, const float* __restrict__ W_time,
    const float* __restrict__ b_time, float* __restrict__ ws) {
  const int tid = threadIdx.x;
  if (tid < NB * NC) {
    const int b = tid / NC, c = tid % NC;
    float s = b_time[c];
    #pragma unroll 4
    for (int k = 0; k < NT; ++k) s = fmaf(t[b * NT + k], W_time[c * NT + k], s);
    ws[tid] = s;
  }
  float* aift_p = ws + 64;
  float* aftT_p = ws + 64 + NG * FP;
  for (int i = tid; i < NG * FP; i += 256) {
    const int g = i / FP, f = i % FP;
    aift_p[i] = (f < NF) ? A_ift[g * NF + f] : 0.0f;
    aftT_p[i] = (f < NF) ? A_ft[f * NG + g] : 0.0f;  // transpose of A_ft
  }
}

// ---------------------------------------------------------------------------
// Fused main kernel: one thread per voxel per (b,c).
// R2 lesson: the compiler sank the xr[] loads into the g-loop (chose 44 VGPRs,
// re-read the x-tile from L2 every 2 g-iters -> 4.5 GB L2 traffic, L2-BW-bound
// at ~29 TB/s). Fix: pin each xr element into a VGPR with an asm "+v" barrier
// right after the load -- the asm output becomes the source of truth, so the
// load cannot be rematerialized later.
// ---------------------------------------------------------------------------
__global__ __launch_bounds__(256, 4) void fta_fused(
    const float* __restrict__ x_hat, const float* __restrict__ ws,
    float* __restrict__ out) {
  const int bc  = blockIdx.y;                       // 0..63  (b*C + c)
  const int vox = blockIdx.x * 256 + threadIdx.x;   // 0..13823 (54*256 exact)

  const float tb = ws[bc];
  const float* __restrict__ aift = (const float*)__builtin_assume_aligned(ws + 64, 16);
  const float* __restrict__ aftT = (const float*)__builtin_assume_aligned(ws + 64 + NG * FP, 16);

  const float* __restrict__ xp = x_hat + (size_t)bc * NF * ND3 + vox;

  float xr[NF];
  #pragma unroll
  for (int f = 0; f < NF; ++f) xr[f] = xp[(size_t)f * ND3];
  // Pin the x-tile in VGPRs: forbid load sinking / rematerialization.
  #pragma unroll
  for (int f = 0; f < NF; ++f) asm volatile("" : "+v"(xr[f]));

  float acc[NF];
  #pragma unroll
  for (int f = 0; f < NF; ++f) acc[f] = 0.0f;

  #pragma unroll 2
  for (int g = 0; g < NG; ++g) {
    const float* __restrict__ arow = aift + g * FP;

    // 4-way split dot: ~9-deep dependent FMA chains instead of 35-deep.
    float v0 = tb, v1 = 0.0f, v2 = 0.0f, v3 = 0.0f;
    #pragma unroll
    for (int f = 0; f < 32; f += 4) {
      v0 = fmaf(arow[f + 0], xr[f + 0], v0);
      v1 = fmaf(arow[f + 1], xr[f + 1], v1);
      v2 = fmaf(arow[f + 2], xr[f + 2], v2);
      v3 = fmaf(arow[f + 3], xr[f + 3], v3);
    }
    v0 = fmaf(arow[32], xr[32], v0);
    v1 = fmaf(arow[33], xr[33], v1);
    v2 = fmaf(arow[34], xr[34], v2);
    const float v = (v0 + v1) + (v2 + v3);

    // SELU: lambda * (v > 0 ? v : alpha*(exp(v)-1))
    const float e   = __expf(v);
    const float neg = fmaf(SELU_LA, e, -SELU_LA);   // lambda*alpha*(e-1)
    const float pos = SELU_LAMBDA * v;
    const float y   = (v > 0.0f) ? pos : neg;

    const float* __restrict__ brow = aftT + g * FP;
    #pragma unroll
    for (int f = 0; f < NF; ++f) acc[f] = fmaf(brow[f], y, acc[f]);
  }

  float* __restrict__ op = out + (size_t)bc * NF * ND3 + vox;
  #pragma unroll
  for (int f = 0; f < NF; ++f) op[(size_t)f * ND3] = acc[f];
}

extern "C" void kernel_launch(void* const* d_in, const int* in_sizes, int n_in,
                              void* d_out, int out_size, void* d_ws, size_t ws_size,
                              hipStream_t stream) {
  const float* x_hat  = (const float*)d_in[0];
  const float* t      = (const float*)d_in[1];
  const float* A_ift  = (const float*)d_in[2];
  const float* A_ft   = (const float*)d_in[3];
  const float* W_time = (const float*)d_in[4];
  const float* b_time = (const float*)d_in[5];
  float* out = (float*)d_out;
  float* ws  = (float*)d_ws;   // needs 64 + 2*72*36 = 5248 floats = 21 KB

  fta_prep<<<1, 256, 0, stream>>>(t, A_ift, A_ft, W_time, b_time, ws);

  dim3 grid(ND3 / 256, NB * NC);   // (54, 64)
  fta_fused<<<grid, 256, 0, stream>>>(x_hat, ws, out);
}

// Round 4
// 150.164 us; speedup vs baseline: 1.0494x; 1.0334x over previous
//
#include <hip/hip_runtime.h>
#include <hip/hip_bf16.h>

// Problem constants: B=4, C=16, F=35, G=72, D=24, T=256
#define NB 4
#define NC 16
#define NF 35
#define NG 72
#define ND3 13824   // 24^3
#define NT 256

typedef float v2f __attribute__((ext_vector_type(2)));

// SELU constants (match jax.nn.selu)
#define SELU_LAMBDA 1.0507009873554805f
#define SELU_LA     1.7580993408473766f   // lambda * alpha

// ws layout (floats):
//   [0,64)              tb[b*C+c]
//   [AD_OFF, +35*36*2)  Adp: [f][36] float2 pairs {A_ift[2j+0][f], A_ift[2j+1][f]}  (packed over g)
//   [BP_OFF, +72*18*2)  Bpk: [g][18] float2 pairs {A_ft[2k+0][g], A_ft[2k+1][g]}    (packed over f, f=35 slot zero)
#define AD_OFF 64
#define BP_OFF (64 + NF * 36 * 2)   // 64 + 2520 = 2584
// total: 2584 + 72*18*2 = 5176 floats = 20.7 KB

// ---------------------------------------------------------------------------
// Prep kernel: tb = t @ W_time^T + b_time; pair-packed matrix copies.
// ---------------------------------------------------------------------------
__global__ __launch_bounds__(256) void fta_prep(
    const float* __restrict__ t, const float* __restrict__ A_ift,
    const float* __restrict__ A_ft, const float* __restrict__ W_time,
    const float* __restrict__ b_time, float* __restrict__ ws) {
  const int tid = threadIdx.x;
  if (tid < NB * NC) {
    const int b = tid / NC, c = tid % NC;
    float s = b_time[c];
    #pragma unroll 4
    for (int k = 0; k < NT; ++k) s = fmaf(t[b * NT + k], W_time[c * NT + k], s);
    ws[tid] = s;
  }
  v2f* Adp = (v2f*)(ws + AD_OFF);
  v2f* Bpk = (v2f*)(ws + BP_OFF);
  for (int i = tid; i < NF * 36; i += 256) {     // i = f*36 + j  (j = g-pair)
    const int f = i / 36, j = i % 36;
    v2f p;
    p.x = A_ift[(2 * j + 0) * NF + f];
    p.y = A_ift[(2 * j + 1) * NF + f];
    Adp[i] = p;
  }
  for (int i = tid; i < NG * 18; i += 256) {     // i = g*18 + k  (k = f-pair)
    const int g = i / 18, k = i % 18;
    const int f0 = 2 * k, f1 = 2 * k + 1;
    v2f p;
    p.x = A_ft[f0 * NG + g];
    p.y = (f1 < NF) ? A_ft[f1 * NG + g] : 0.0f;
    Bpk[i] = p;
  }
}

__device__ __forceinline__ float selu_f(float v) {
  const float e   = __expf(v);
  const float neg = fmaf(SELU_LA, e, -SELU_LA);   // lambda*alpha*(e-1)
  const float pos = SELU_LAMBDA * v;
  return (v > 0.0f) ? pos : neg;
}

// ---------------------------------------------------------------------------
// Fused main kernel, R4 structure:
//  - x-tile staged ONCE into LDS (software-managed; compiler cannot sink it).
//    xs[f][tid]: each thread writes/reads only its own column -> no barrier,
//    no bank conflicts (lanes consecutive, 2 lanes/bank = free).
//  - g-blocked (GB=8): per block of 8 g's, each xs[f] is read once from LDS
//    and reused by 8 FMAs. Live set = acc(36) + v(8) + y(8) + temps ~= 70
//    VGPRs -- small by construction, nothing for the allocator to spill.
//  - both FMA streams packed as float2 (v_pk_fma_f32): dot packed over g
//    (x broadcast), accumulate packed over f (y broadcast). Matrix pairs are
//    wave-uniform s_load_dwordx2 through the scalar pipe.
// ---------------------------------------------------------------------------
__global__ __launch_bounds__(256, 4) void fta_fused(
    const float* __restrict__ x_hat, const float* __restrict__ ws,
    float* __restrict__ out) {
  __shared__ float xs[NF][256];

  const int tid = threadIdx.x;
  const int bc  = blockIdx.y;                       // 0..63
  const int vox = blockIdx.x * 256 + tid;           // 0..13823

  const float tb = ws[bc];
  const v2f* __restrict__ Adp = (const v2f*)(ws + AD_OFF);
  const v2f* __restrict__ Bpk = (const v2f*)(ws + BP_OFF);

  // Stage x-tile: 35 coalesced global loads -> LDS.
  const float* __restrict__ xp = x_hat + (size_t)bc * NF * ND3 + vox;
  #pragma unroll
  for (int f = 0; f < NF; ++f) xs[f][tid] = xp[(size_t)f * ND3];

  v2f acc[18];
  #pragma unroll
  for (int k = 0; k < 18; ++k) acc[k] = (v2f){0.0f, 0.0f};

  #pragma unroll 1
  for (int gb = 0; gb < 9; ++gb) {
    // ---- dot: v[g] for 8 g's, packed as 4 float2 ----
    v2f v0 = {tb, tb}, v1 = {tb, tb}, v2 = {tb, tb}, v3 = {tb, tb};
    #pragma unroll
    for (int f = 0; f < NF; ++f) {
      const float xv = xs[f][tid];         // 1 ds_read_b32, reused 8x
      const v2f xb = {xv, xv};
      const v2f* __restrict__ ap = Adp + f * 36 + gb * 4;
      v0 = __builtin_elementwise_fma(ap[0], xb, v0);
      v1 = __builtin_elementwise_fma(ap[1], xb, v1);
      v2 = __builtin_elementwise_fma(ap[2], xb, v2);
      v3 = __builtin_elementwise_fma(ap[3], xb, v3);
    }
    // ---- SELU ----
    float y[8];
    y[0] = selu_f(v0.x); y[1] = selu_f(v0.y);
    y[2] = selu_f(v1.x); y[3] = selu_f(v1.y);
    y[4] = selu_f(v2.x); y[5] = selu_f(v2.y);
    y[6] = selu_f(v3.x); y[7] = selu_f(v3.y);
    // ---- accumulate: acc[f-pair] += B[g][f-pair] * y[g] ----
    #pragma unroll
    for (int j = 0; j < 8; ++j) {
      const v2f yb = {y[j], y[j]};
      const v2f* __restrict__ bp = Bpk + (gb * 8 + j) * 18;
      #pragma unroll
      for (int k = 0; k < 18; ++k)
        acc[k] = __builtin_elementwise_fma(bp[k], yb, acc[k]);
    }
  }

  // Store: pairs are (2k, 2k+1) in f; f=35 slot is padding.
  float* __restrict__ op = out + (size_t)bc * NF * ND3 + vox;
  #pragma unroll
  for (int k = 0; k < 17; ++k) {
    op[(size_t)(2 * k + 0) * ND3] = acc[k].x;
    op[(size_t)(2 * k + 1) * ND3] = acc[k].y;
  }
  op[(size_t)34 * ND3] = acc[17].x;
}

extern "C" void kernel_launch(void* const* d_in, const int* in_sizes, int n_in,
                              void* d_out, int out_size, void* d_ws, size_t ws_size,
                              hipStream_t stream) {
  const float* x_hat  = (const float*)d_in[0];
  const float* t      = (const float*)d_in[1];
  const float* A_ift  = (const float*)d_in[2];
  const float* A_ft   = (const float*)d_in[3];
  const float* W_time = (const float*)d_in[4];
  const float* b_time = (const float*)d_in[5];
  float* out = (float*)d_out;
  float* ws  = (float*)d_ws;   // needs 5176 floats = 20.7 KB

  fta_prep<<<1, 256, 0, stream>>>(t, A_ift, A_ft, W_time, b_time, ws);

  dim3 grid(ND3 / 256, NB * NC);   // (54, 64)
  fta_fused<<<grid, 256, 0, stream>>>(x_hat, ws, out);
}

// Round 5
// 105.844 us; speedup vs baseline: 1.4888x; 1.4187x over previous
//
#include <hip/hip_runtime.h>
#include <hip/hip_bf16.h>

// Problem constants: B=4, C=16, F=35, G=72, D=24, T=256
#define NB 4
#define NC 16
#define NF 35
#define NG 72
#define ND3 13824   // 24^3
#define NT 256

typedef __bf16 bf16x8 __attribute__((ext_vector_type(8)));
typedef float  f32x4  __attribute__((ext_vector_type(4)));
typedef unsigned short ushort_t;
typedef unsigned int   uint_t;

// SELU constants (match jax.nn.selu)
#define SELU_LAMBDA 1.0507009873554805f
#define SELU_LA     1.7580993408473766f   // lambda * alpha

// ws layout (bytes):
//   [0,256)    tb[64] fp32
//   [256, +80*64*2)   A1p: A_ift padded to [80][64] bf16 row-major (g rows >=72 zero, f cols >=35 zero)
//   [.., +48*96*2)    A2p: A_ft  padded to [48][96] bf16 row-major (f' rows >=35 zero, g cols >=72 zero)
// total 256 + 10240 + 9216 = 19712 B

__device__ __forceinline__ ushort_t f2bf(float x) {
  uint_t u = __builtin_bit_cast(uint_t, x);
  u = (u + 0x7FFFu + ((u >> 16) & 1u)) >> 16;   // RTNE
  return (ushort_t)u;
}

__device__ __forceinline__ float selu_f(float v) {
  const float e   = __expf(v);
  const float neg = fmaf(SELU_LA, e, -SELU_LA);   // lambda*alpha*(e-1)
  const float pos = SELU_LAMBDA * v;
  return (v > 0.0f) ? pos : neg;
}

// ---------------------------------------------------------------------------
// Prep: tb = t @ W_time^T + b_time; zero-padded bf16 copies of A_ift / A_ft.
// ---------------------------------------------------------------------------
__global__ __launch_bounds__(256) void fta_prep(
    const float* __restrict__ t, const float* __restrict__ A_ift,
    const float* __restrict__ A_ft, const float* __restrict__ W_time,
    const float* __restrict__ b_time, float* __restrict__ ws) {
  const int tid = threadIdx.x;
  if (tid < NB * NC) {
    const int b = tid / NC, c = tid % NC;
    float s = b_time[c];
    #pragma unroll 4
    for (int k = 0; k < NT; ++k) s = fmaf(t[b * NT + k], W_time[c * NT + k], s);
    ws[tid] = s;
  }
  ushort_t* A1 = (ushort_t*)(ws + 64);
  ushort_t* A2 = A1 + 80 * 64;
  for (int i = tid; i < 80 * 64; i += 256) {          // [g][f]
    const int g = i >> 6, f = i & 63;
    A1[i] = (g < NG && f < NF) ? f2bf(A_ift[g * NF + f]) : (ushort_t)0;
  }
  for (int i = tid; i < 48 * 96; i += 256) {          // [f'][g]
    const int fp = i / 96, g = i % 96;
    A2[i] = (fp < NF && g < NG) ? f2bf(A_ft[fp * NG + g]) : (ushort_t)0;
  }
}

// ---------------------------------------------------------------------------
// MFMA fused kernel. Block = 4 waves; wave owns 64 voxels (4 tiles of 16)
// for one (b,c). Per 16-voxel tile:
//   1. stage X (35 f-rows x 16 vox) fp32->bf16 into wave-private LDS [16][72]
//   2. GEMM1: S(80x16) = A1p(80x64) * X(64x16), 10 mfma, C-init = tb
//   3. SELU on 20 regs/lane, pack bf16 pairs -> LDS Y [16][104] (pad g>=72 = 0)
//   4. GEMM2: O(48x16) = A2p(48x96) * Y(96x16), 9 mfma (A2 streamed from L1)
//   5. predicated stores of f' < 35 rows
// Fragment layouts (gfx950 16x16x32 bf16): A: a[i]=A[l&15][8*(l>>4)+i];
// B: b[i]=B[8*(l>>4)+i][l&15]; C/D: col=l&15, row=4*(l>>4)+j  [m89 verified].
// All LDS traffic is wave-private -> no barriers (DS pipe is in-order per wave).
// ---------------------------------------------------------------------------
__global__ __launch_bounds__(256, 4) void fta_mfma(
    const float* __restrict__ x_hat, const float* __restrict__ ws,
    float* __restrict__ out) {
  __shared__ __align__(16) ushort_t Xs[4][16][72];    //  9216 B (f-pad 35..63 = 0)
  __shared__ __align__(16) ushort_t Ys[4][16][104];   // 13312 B (g-pad 72..95 = 0)

  const int tid  = threadIdx.x;
  const int w    = tid >> 6;
  const int lane = tid & 63;
  const int v16  = lane & 15;      // voxel-in-tile / matrix column
  const int q    = lane >> 4;      // lane quad
  const int bc   = blockIdx.y;

  const float tb = ws[bc];
  const ushort_t* __restrict__ A1p = (const ushort_t*)(ws + 64);
  const ushort_t* __restrict__ A2p = A1p + 80 * 64;

  // A1 fragments resident in registers (40 VGPRs)
  bf16x8 a1[5][2];
  #pragma unroll
  for (int mt = 0; mt < 5; ++mt)
    #pragma unroll
    for (int ks = 0; ks < 2; ++ks)
      a1[mt][ks] = *(const bf16x8*)(A1p + (16 * mt + v16) * 64 + 32 * ks + 8 * q);

  // zero wave-private LDS once (establishes the zero pads)
  {
    uint_t* xz = (uint_t*)&Xs[w][0][0];
    for (int i = lane; i < 576; i += 64) xz[i] = 0;
    uint_t* yz = (uint_t*)&Ys[w][0][0];
    for (int i = lane; i < 832; i += 64) yz[i] = 0;
  }
  ushort_t (* __restrict__ Xw)[72]  = Xs[w];
  ushort_t (* __restrict__ Yw)[104] = Ys[w];

  #pragma unroll 1
  for (int it = 0; it < 4; ++it) {
    const int voxbase = blockIdx.x * 256 + w * 64 + it * 16;
    const float* __restrict__ xp = x_hat + (size_t)bc * (NF * ND3) + voxbase;

    // ---- stage X: rows f = 4i+q, cols v16 (coalesced 16-lane segments) ----
    #pragma unroll
    for (int i = 0; i < 9; ++i) {
      const int f = i * 4 + q;
      if (f < NF) Xw[v16][f] = f2bf(xp[(size_t)f * ND3 + v16]);
    }

    // ---- GEMM1: S = A1p * X + tb ----
    f32x4 acc[5];
    #pragma unroll
    for (int mt = 0; mt < 5; ++mt) acc[mt] = (f32x4){tb, tb, tb, tb};
    const bf16x8 bx0 = *(const bf16x8*)&Xw[v16][8 * q];
    const bf16x8 bx1 = *(const bf16x8*)&Xw[v16][32 + 8 * q];
    #pragma unroll
    for (int mt = 0; mt < 5; ++mt) {
      acc[mt] = __builtin_amdgcn_mfma_f32_16x16x32_bf16(a1[mt][0], bx0, acc[mt], 0, 0, 0);
      acc[mt] = __builtin_amdgcn_mfma_f32_16x16x32_bf16(a1[mt][1], bx1, acc[mt], 0, 0, 0);
    }

    // ---- SELU -> bf16 pairs -> Y in LDS (rows g = 16mt+4q+j) ----
    #pragma unroll
    for (int mt = 0; mt < 5; ++mt) {
      const bool wr = (mt < 4) || (q < 2);   // keep g >= 72 pad zero
      #pragma unroll
      for (int jp = 0; jp < 2; ++jp) {
        const float y0 = selu_f(acc[mt][2 * jp + 0]);
        const float y1 = selu_f(acc[mt][2 * jp + 1]);
        const uint_t pk = (uint_t)f2bf(y0) | ((uint_t)f2bf(y1) << 16);
        if (wr) *(uint_t*)&Yw[v16][16 * mt + 4 * q + 2 * jp] = pk;
      }
    }

    // ---- GEMM2: O = A2p * Y (A2 fragments streamed from L1) ----
    f32x4 o[3];
    #pragma unroll
    for (int m2 = 0; m2 < 3; ++m2) o[m2] = (f32x4){0.f, 0.f, 0.f, 0.f};
    #pragma unroll
    for (int ks2 = 0; ks2 < 3; ++ks2) {
      const bf16x8 by = *(const bf16x8*)&Yw[v16][32 * ks2 + 8 * q];
      #pragma unroll
      for (int m2 = 0; m2 < 3; ++m2) {
        const bf16x8 a2 = *(const bf16x8*)(A2p + (16 * m2 + v16) * 96 + 32 * ks2 + 8 * q);
        o[m2] = __builtin_amdgcn_mfma_f32_16x16x32_bf16(a2, by, o[m2], 0, 0, 0);
      }
    }

    // ---- store rows f' = 16m2+4q+j, col v16 ----
    float* __restrict__ op = out + (size_t)bc * (NF * ND3) + voxbase + v16;
    #pragma unroll
    for (int m2 = 0; m2 < 3; ++m2)
      #pragma unroll
      for (int j = 0; j < 4; ++j) {
        const int fp = 16 * m2 + 4 * q + j;
        if (fp < NF) op[(size_t)fp * ND3] = o[m2][j];
      }
  }
}

extern "C" void kernel_launch(void* const* d_in, const int* in_sizes, int n_in,
                              void* d_out, int out_size, void* d_ws, size_t ws_size,
                              hipStream_t stream) {
  const float* x_hat  = (const float*)d_in[0];
  const float* t      = (const float*)d_in[1];
  const float* A_ift  = (const float*)d_in[2];
  const float* A_ft   = (const float*)d_in[3];
  const float* W_time = (const float*)d_in[4];
  const float* b_time = (const float*)d_in[5];
  float* out = (float*)d_out;
  float* ws  = (float*)d_ws;   // needs 19712 B

  fta_prep<<<1, 256, 0, stream>>>(t, A_ift, A_ft, W_time, b_time, ws);

  dim3 grid(ND3 / 256, NB * NC);   // (54, 64)
  fta_mfma<<<grid, 256, 0, stream>>>(x_hat, ws, out);
}

// Round 6
// 74.602 us; speedup vs baseline: 2.1122x; 1.4188x over previous
//
#include <hip/hip_runtime.h>
#include <hip/hip_bf16.h>

// Problem constants: B=4, C=16, F=35, G=72, D=24, T=256
#define NB 4
#define NC 16
#define NF 35
#define NG 72
#define ND3 13824   // 24^3
#define NT 256

typedef __bf16 bf16x8 __attribute__((ext_vector_type(8)));
typedef float  f32x4  __attribute__((ext_vector_type(4)));
typedef unsigned int uint4v __attribute__((ext_vector_type(4)));
typedef unsigned short ushort_t;
typedef unsigned int   uint_t;

// SELU constants (match jax.nn.selu)
#define SELU_LAMBDA 1.0507009873554805f
#define SELU_LA     1.7580993408473766f   // lambda * alpha

// ws layout (bytes):
//   [0,256)          tb[64] fp32
//   [256,+80*64*2)   A1p: A_ift padded to [80][64] bf16 (g>=72 rows, f>=35 cols zero)
//   [..,+48*96*2)    A2p: A_ft  padded to [48][96] bf16 (f>=35 rows, g>=72 cols zero)

__device__ __forceinline__ ushort_t f2bf(float x) {
  uint_t u = __builtin_bit_cast(uint_t, x);
  u = (u + 0x7FFFu + ((u >> 16) & 1u)) >> 16;   // RTNE
  return (ushort_t)u;
}

__device__ __forceinline__ float selu_f(float v) {
  const float e   = __expf(v);
  const float neg = fmaf(SELU_LA, e, -SELU_LA);   // lambda*alpha*(e-1)
  const float pos = SELU_LAMBDA * v;
  return (v > 0.0f) ? pos : neg;
}

__device__ __forceinline__ uint_t cvt_pk_bf16(float lo, float hi) {
  uint_t r;
  asm("v_cvt_pk_bf16_f32 %0, %1, %2" : "=v"(r) : "v"(lo), "v"(hi));
  return r;
}

// ---------------------------------------------------------------------------
// Prep: tb = t @ W_time^T + b_time; zero-padded bf16 copies of A_ift / A_ft.
// ---------------------------------------------------------------------------
__global__ __launch_bounds__(256) void fta_prep(
    const float* __restrict__ t, const float* __restrict__ A_ift,
    const float* __restrict__ A_ft, const float* __restrict__ W_time,
    const float* __restrict__ b_time, float* __restrict__ ws) {
  const int tid = threadIdx.x;
  if (tid < NB * NC) {
    const int b = tid / NC, c = tid % NC;
    float s = b_time[c];
    #pragma unroll 4
    for (int k = 0; k < NT; ++k) s = fmaf(t[b * NT + k], W_time[c * NT + k], s);
    ws[tid] = s;
  }
  ushort_t* A1 = (ushort_t*)(ws + 64);
  ushort_t* A2 = A1 + 80 * 64;
  for (int i = tid; i < 80 * 64; i += 256) {          // [g][f]
    const int g = i >> 6, f = i & 63;
    A1[i] = (g < NG && f < NF) ? f2bf(A_ift[g * NF + f]) : (ushort_t)0;
  }
  for (int i = tid; i < 48 * 96; i += 256) {          // [f'][g]
    const int fp = i / 96, g = i % 96;
    A2[i] = (fp < NF && g < NG) ? f2bf(A_ft[fp * NG + g]) : (ushort_t)0;
  }
}

// ---------------------------------------------------------------------------
// R6: MFMA kernel, latency-optimized.
//  - GEMM1 B-fragment loaded DIRECTLY global->reg (lane(q,v16) reads
//    x[(8q+i)*ND3 + vox+v16], 64B coalesced segments) -- no X LDS hop.
//  - 2-stage pipeline: tile t+1's 11 loads issued before tile t's compute.
//  - bf16 packing via v_cvt_pk_bf16_f32 (1 instr / 2 values).
//  - Y redistribution (C/D layout -> B layout) via wave-private LDS, as R5.
// ---------------------------------------------------------------------------
__global__ __launch_bounds__(256, 4) void fta_mfma(
    const float* __restrict__ x_hat, const float* __restrict__ ws,
    float* __restrict__ out) {
  __shared__ __align__(16) ushort_t Ys[4][16][104];   // 13312 B

  const int tid  = threadIdx.x;
  const int w    = tid >> 6;
  const int lane = tid & 63;
  const int v16  = lane & 15;      // voxel-in-tile / matrix column
  const int q    = lane >> 4;      // lane quad
  const int bc   = blockIdx.y;

  const float tb = ws[bc];
  const ushort_t* __restrict__ A1p = (const ushort_t*)(ws + 64);
  const ushort_t* __restrict__ A2p = A1p + 80 * 64;

  // A1 fragments register-resident (40 VGPRs)
  bf16x8 a1[5][2];
  #pragma unroll
  for (int mt = 0; mt < 5; ++mt)
    #pragma unroll
    for (int ks = 0; ks < 2; ++ks)
      a1[mt][ks] = *(const bf16x8*)(A1p + (16 * mt + v16) * 64 + 32 * ks + 8 * q);

  // zero wave-private Y buffer once (establishes g>=72 pad)
  {
    uint_t* yz = (uint_t*)&Ys[w][0][0];
    #pragma unroll 1
    for (int i = lane; i < 832; i += 64) yz[i] = 0;
  }
  ushort_t (* __restrict__ Yw)[104] = Ys[w];

  const float* __restrict__ xbase =
      x_hat + (size_t)bc * (NF * ND3) + blockIdx.x * 256 + w * 64 + v16;
  float* __restrict__ obase =
      out + (size_t)bc * (NF * ND3) + blockIdx.x * 256 + w * 64 + v16;

  float xrA[8], xtA[3], xrB[8], xtB[3];

  auto LOADX = [&](float (&xr)[8], float (&xt)[3], int it) {
    const float* __restrict__ xp = xbase + it * 16;
    #pragma unroll
    for (int i = 0; i < 8; ++i) xr[i] = xp[(size_t)(8 * q + i) * ND3];
    xt[0] = xt[1] = xt[2] = 0.0f;
    if (q == 0) {
      #pragma unroll
      for (int i = 0; i < 3; ++i) xt[i] = xp[(size_t)(32 + i) * ND3];
    }
  };

  auto COMPUTE = [&](const float (&xr)[8], const float (&xt)[3], int it) {
    // ---- pack B fragments (k = 8q+i | 32+8q+i) ----
    uint4v u0;
    u0.x = cvt_pk_bf16(xr[0], xr[1]);
    u0.y = cvt_pk_bf16(xr[2], xr[3]);
    u0.z = cvt_pk_bf16(xr[4], xr[5]);
    u0.w = cvt_pk_bf16(xr[6], xr[7]);
    uint4v u1;
    u1.x = cvt_pk_bf16(xt[0], xt[1]);   // zero on q!=0 lanes
    u1.y = cvt_pk_bf16(xt[2], 0.0f);
    u1.z = 0; u1.w = 0;
    const bf16x8 bx0 = __builtin_bit_cast(bf16x8, u0);
    const bf16x8 bx1 = __builtin_bit_cast(bf16x8, u1);

    // ---- GEMM1: S(80x16) = A1p * X, C-init = tb ----
    f32x4 acc[5];
    #pragma unroll
    for (int mt = 0; mt < 5; ++mt) acc[mt] = (f32x4){tb, tb, tb, tb};
    #pragma unroll
    for (int mt = 0; mt < 5; ++mt) {
      acc[mt] = __builtin_amdgcn_mfma_f32_16x16x32_bf16(a1[mt][0], bx0, acc[mt], 0, 0, 0);
      acc[mt] = __builtin_amdgcn_mfma_f32_16x16x32_bf16(a1[mt][1], bx1, acc[mt], 0, 0, 0);
    }

    // ---- SELU -> bf16 pairs -> Yw (rows g = 16mt+4q+2jp) ----
    #pragma unroll
    for (int mt = 0; mt < 5; ++mt) {
      const bool wr = (mt < 4) || (q < 2);   // keep g>=72 pad zero
      #pragma unroll
      for (int jp = 0; jp < 2; ++jp) {
        const float y0 = selu_f(acc[mt][2 * jp + 0]);
        const float y1 = selu_f(acc[mt][2 * jp + 1]);
        const uint_t pk = cvt_pk_bf16(y0, y1);
        if (wr) *(uint_t*)&Yw[v16][16 * mt + 4 * q + 2 * jp] = pk;
      }
    }

    // ---- GEMM2: O(48x16) = A2p * Y (A2 from L1/L2; loop-invariant) ----
    f32x4 o[3];
    #pragma unroll
    for (int m2 = 0; m2 < 3; ++m2) o[m2] = (f32x4){0.f, 0.f, 0.f, 0.f};
    #pragma unroll
    for (int ks2 = 0; ks2 < 3; ++ks2) {
      const bf16x8 by = *(const bf16x8*)&Yw[v16][32 * ks2 + 8 * q];
      #pragma unroll
      for (int m2 = 0; m2 < 3; ++m2) {
        const bf16x8 a2 = *(const bf16x8*)(A2p + (16 * m2 + v16) * 96 + 32 * ks2 + 8 * q);
        o[m2] = __builtin_amdgcn_mfma_f32_16x16x32_bf16(a2, by, o[m2], 0, 0, 0);
      }
    }

    // ---- store rows f' = 16m2+4q+j ----
    float* __restrict__ op = obase + it * 16;
    #pragma unroll
    for (int m2 = 0; m2 < 3; ++m2)
      #pragma unroll
      for (int j = 0; j < 4; ++j) {
        const int fp = 16 * m2 + 4 * q + j;
        if (fp < NF) op[(size_t)fp * ND3] = o[m2][j];
      }
  };

  // ---- 2-stage software pipeline over the wave's 4 column tiles ----
  LOADX(xrA, xtA, 0);
  LOADX(xrB, xtB, 1);
  COMPUTE(xrA, xtA, 0);
  LOADX(xrA, xtA, 2);
  COMPUTE(xrB, xtB, 1);
  LOADX(xrB, xtB, 3);
  COMPUTE(xrA, xtA, 2);
  COMPUTE(xrB, xtB, 3);
}

extern "C" void kernel_launch(void* const* d_in, const int* in_sizes, int n_in,
                              void* d_out, int out_size, void* d_ws, size_t ws_size,
                              hipStream_t stream) {
  const float* x_hat  = (const float*)d_in[0];
  const float* t      = (const float*)d_in[1];
  const float* A_ift  = (const float*)d_in[2];
  const float* A_ft   = (const float*)d_in[3];
  const float* W_time = (const float*)d_in[4];
  const float* b_time = (const float*)d_in[5];
  float* out = (float*)d_out;
  float* ws  = (float*)d_ws;   // needs 19712 B

  fta_prep<<<1, 256, 0, stream>>>(t, A_ift, A_ft, W_time, b_time, ws);

  dim3 grid(ND3 / 256, NB * NC);   // (54, 64)
  fta_mfma<<<grid, 256, 0, stream>>>(x_hat, ws, out);
}